// Round 10
// baseline (558.339 us; speedup 1.0000x reference)
//
#include <hip/hip_runtime.h>
#include <math.h>

// B=32, Cin=64, H=W=56, Cout=128, K=3 pad=1 -> D=576, out (32,128,56,56) fp32
#define B_    32
#define CIN   64
#define HH    56
#define WW    56
#define COUT  128
#define DD    576
#define KC    384            // OpenBLAS kc split (verified R9)
#define LPX   (HH*WW)        // 3136 = 49*64
#define TOTAL (B_*COUT*LPX)
#define NX    (B_*CIN*LPX)   // 6422528
#define PW    58             // padded plane width/height
#define PPL   (PW*PW)        // 3364 words per padded channel plane
#define NXP   (B_*CIN*PPL)   // 6889472 words
#define MARGIN 4e-4f         // worst-case split-bf16 + reorder bound (validated R15-18)

typedef __attribute__((ext_vector_type(8)))  short  short8;
typedef __attribute__((ext_vector_type(16))) float  float16v;

__device__ __forceinline__ unsigned short bf16_rne(float f) {
    unsigned u = __float_as_uint(f);
    unsigned r = u + 0x7FFFu + ((u >> 16) & 1u);
    return (unsigned short)(r >> 16);
}
__device__ __forceinline__ float bf16_to_f(unsigned short h) {
    return __uint_as_float(((unsigned)h) << 16);
}

// ---- bit-exact numpy FLOAT_sin (npyv FMA path) — verified R9 ----
__device__ __forceinline__ float np_sinf(float x) {
#pragma clang fp contract(off)
    const float rint_cvt = 0x1.8p+23f;
    float q = __fmul_rn(x, 0x1.45f306p-1f);
    q = __fadd_rn(q, rint_cvt);
    q = __fsub_rn(q, rint_cvt);
    float r = fmaf(q, -0x1.921fb0p+0f, x);
    r = fmaf(q, -0x1.5110b4p-22f, r);
    r = fmaf(q, -0x1.846988p-48f, r);
    float r2 = __fmul_rn(r, r);
    float s = fmaf(0x1.7d3bbcp-19f, r2, -0x1.a06bbap-13f);
    s = fmaf(s, r2, 0x1.11119ap-7f);
    s = fmaf(s, r2, -0x1.555556p-3f);
    s = __fmul_rn(s, r2);
    s = fmaf(s, r, r);
    float c = fmaf(0x1.98e616p-16f, r2, -0x1.6c06dcp-10f);
    c = fmaf(c, r2, 0x1.55553cp-5f);
    c = fmaf(c, r2, -0.5f);
    c = fmaf(c, r2, 1.0f);
    int iq = (int)q;
    float res = (iq & 1) ? c : s;
    unsigned sgn = ((unsigned)(iq & 2)) << 30;
    return __uint_as_float(__float_as_uint(res) ^ sgn);
}
__device__ __forceinline__ int dec_np(float z) {
    float s = np_sinf(z);
    return (__fmul_rn(s, s) > 0.5f) ? 1 : 0;
}

// ---- exact recompute for margin-flagged outputs: IDENTICAL order to the
// verified R9 np_emul path (c ascending, u, v; kc=384 split; rn adds) ->
// bit-identical z -> bit-exact decision. noinline: one copy, called rarely.
__device__ __attribute__((noinline)) float exact_bit(
    const float* __restrict__ x, const float* __restrict__ Wt,
    const float* __restrict__ bias, int b, int o, int py, int px) {
#pragma clang fp contract(off)
    const float* wrow = Wt + (size_t)o * DD;
    const float* xb   = x + (size_t)b * CIN * LPX;
    float accA = 0.f, accB2 = 0.f;
    for (int c = 0; c < CIN; ++c) {
        const float* xc = xb + c * LPX;
        const float* wc = wrow + c * 9;
        int dbase = c * 9;
#pragma unroll
        for (int u = 0; u < 3; ++u)
#pragma unroll
            for (int v = 0; v < 3; ++v) {
                int tp = u * 3 + v;
                int gy = py + u - 1, gx = px + v - 1;
                float p = ((unsigned)gy < HH && (unsigned)gx < WW)
                              ? xc[gy * WW + gx] : 0.f;
                if (dbase + tp < KC) accA  = fmaf(p, wc[tp], accA);
                else                 accB2 = fmaf(p, wc[tp], accB2);
            }
    }
    float z = __fadd_rn(__fadd_rn(accA, accB2), bias[o]);
    return (float)dec_np(z);
}

// ---- merged prep (x4 vectorized): W -> fragment-major bf16 hi/lo pack,
// x -> padded 58x58 planes of (hi | lo<<16) u32 words, borders zero ----
// W dst for (o,k): k18=k/32, kr=k%32, s=kr/16, half=(kr%16)/8, j=kr%8
//   lane = half*32 + (o%32), ot = o/32
//   idx  = (((k18*4 + ot)*2 + s)*64 + lane)*8 + j
__global__ __launch_bounds__(256)
void prep_all(const float* __restrict__ x, const float* __restrict__ W,
              unsigned* __restrict__ xpad,
              unsigned short* __restrict__ Wph, unsigned short* __restrict__ Wpl) {
    int i4 = (blockIdx.x * 256 + threadIdx.x) * 4;
    if (i4 < COUT * DD) {               // COUT*DD % 4 == 0
#pragma unroll
        for (int e = 0; e < 4; ++e) {
            int i = i4 + e;
            int o = i / DD, k = i - o * DD;
            float w = W[i];
            unsigned short h = bf16_rne(w);
            unsigned short l = bf16_rne(w - bf16_to_f(h));
            int k18 = k >> 5, kr = k & 31;
            int s = (kr >> 4) & 1, half = (kr >> 3) & 1, j = kr & 7;
            int lane = half * 32 + (o & 31);
            int ot = o >> 5;
            unsigned dst = ((((unsigned)(k18 * 4 + ot)) * 2 + s) * 64 + lane) * 8 + j;
            Wph[dst] = h;
            Wpl[dst] = l;
        }
    }
    if (i4 < NXP) {                      // NXP % 4 == 0
        unsigned vv[4];
#pragma unroll
        for (int e = 0; e < 4; ++e) {
            int i = i4 + e;
            int bc = i / PPL;
            int r  = i - bc * PPL;
            int yy = r / PW;
            int xx = r - yy * PW;
            unsigned v = 0u;
            if (yy >= 1 && yy <= HH && xx >= 1 && xx <= WW) {
                float f = x[(size_t)bc * LPX + (yy - 1) * WW + (xx - 1)];
                unsigned short h = bf16_rne(f);
                unsigned short l = bf16_rne(f - bf16_to_f(h));
                v = (unsigned)h | ((unsigned)l << 16);
            }
            vv[e] = v;
        }
        *(uint4*)(xpad + i4) = *(uint4*)vv;
    }
}

// ---- MFMA conv: 64px x 128out tile, 4 waves (R5 structure — best measured).
// Changes vs R5: (1) launch_bounds(256,6) + A-prefetch dropped -> 6 blocks/CU
// resident; grid = 6.125 blocks/CU -> whole grid co-resident, occupancy ~75%
// (R9 diagnosis: latency-bound at 4 blocks/CU, 18K-cyc waits per 1.5K work).
// (2) margin fixup inlined in epilogue (bit-exact np order) -> fix kernel
// and its launch deleted; no atomics/wlist.
// Per-acc MFMA order identical to R5 -> bit-identical acc -> MARGIN valid.
#define FRAG(t, s, hf, ln)  (((t) * 1024) + ((s) * 512) + ((hf) * 256) + ((ln) * 8))
__global__ __launch_bounds__(256, 6)
void conv_mfma(const unsigned* __restrict__ xpad,
               const unsigned short* __restrict__ Wph,
               const unsigned short* __restrict__ Wpl,
               const float* __restrict__ bias,
               float* __restrict__ out,
               const float* __restrict__ x,
               const float* __restrict__ Wt) {
    __shared__ __align__(16) unsigned short sPh[2][2048];
    __shared__ __align__(16) unsigned short sPl[2][2048];

    const int tid = threadIdx.x;
    // XCD-chunked bijective swizzle (1568 = 8*196): per-XCD contiguous chunk
    // = exactly 4 batches of xpad (~3.4MB -> fits 4MB L2).
    const int bid = (blockIdx.x & 7) * 196 + (blockIdx.x >> 3);
    const int pt0 = bid * 64;            // 64-px tile, never crosses a batch

    const int plane = tid & 15;
    const int pair  = tid >> 4;
    const int s_st  = pair >> 3;
    const int h_st  = (pair >> 2) & 1;
    const int j2_st = pair & 3;

    // per-r pixel bases into padded x (b folded in; LPX%64==0 so b-uniform)
    unsigned pbase[4];
#pragma unroll
    for (int r = 0; r < 4; ++r) {
        int gp = pt0 + plane + r * 16;
        int br = gp / LPX;
        int pr = gp - br * LPX;
        int ypx = pr / WW;
        int xpx = pr - ypx * WW;
        pbase[r] = (unsigned)(br * (CIN * PPL) + ypx * PW + xpx);
    }

    const int w    = tid >> 6;           // o-tile (0..3)
    const int lane = tid & 63;
    const int lm   = lane & 31;
    const int half = lane >> 5;
    const uint4* wAh = (const uint4*)Wph + w * 128 + lane;
    const uint4* wAl = (const uint4*)Wpl + w * 128 + lane;

    float16v acc[2];
#pragma unroll
    for (int n = 0; n < 2; ++n)
#pragma unroll
        for (int i = 0; i < 16; ++i) acc[n][i] = 0.f;

    unsigned pg[4][2], pgn[4][2];
    uint4 Ah[2], Al[2];

#define LOADP(K0, DST)                                                         \
    {                                                                          \
        int d0 = (K0) + pair * 2;                                              \
        int c0 = d0 / 9, t0 = d0 - c0 * 9;                                     \
        int u0 = t0 / 3, v0 = t0 - u0 * 3;                                     \
        int t1 = t0 + 1, c1 = c0;                                              \
        if (t1 == 9) { t1 = 0; c1 = c0 + 1; }                                  \
        int u1 = t1 / 3, v1 = t1 - u1 * 3;                                     \
        unsigned off0 = (unsigned)(c0 * PPL + u0 * PW + v0);                   \
        unsigned off1 = (unsigned)(c1 * PPL + u1 * PW + v1);                   \
        _Pragma("unroll")                                                      \
        for (int r = 0; r < 4; ++r) {                                          \
            DST[r][0] = xpad[pbase[r] + off0];                                 \
            DST[r][1] = xpad[pbase[r] + off1];                                 \
        }                                                                      \
    }

    LOADP(0, pg)

#pragma unroll
    for (int it = 0; it < 18; ++it) {
        unsigned short* bPh = sPh[it & 1];
        unsigned short* bPl = sPl[it & 1];

        // publish step it's patches (prefetched regs -> LDS)
#pragma unroll
        for (int r = 0; r < 4; ++r) {
            unsigned g0 = pg[r][0], g1 = pg[r][1];
            unsigned hw = (g0 & 0xFFFFu) | (g1 << 16);
            unsigned lw = (g0 >> 16) | (g1 & 0xFFFF0000u);
            int pm = plane + (r & 1) * 16;
            int word = (r >> 1) * 512 + s_st * 256 + h_st * 128 + pm * 4 + j2_st;
            ((unsigned*)bPh)[word] = hw;
            ((unsigned*)bPl)[word] = lw;
        }

        // issue this step's A loads (L2-hot; in flight across the barrier,
        // consumed after the LDS reads — TLP at 24 waves/CU covers them)
#pragma unroll
        for (int s = 0; s < 2; ++s) {
            Ah[s] = wAh[it * 512 + s * 64];
            Al[s] = wAl[it * 512 + s * 64];
        }

        // issue next step's patch gathers (land under the MFMA phase)
        if (it < 17) { LOADP((it + 1) * 32, pgn) }

        // drain own ds ops, rendezvous; global loads stay in flight
        asm volatile("s_waitcnt lgkmcnt(0)" ::: "memory");
        __builtin_amdgcn_s_barrier();
        asm volatile("" ::: "memory");

#pragma unroll
        for (int n = 0; n < 2; ++n) {
            short8 Bh0 = *(const short8*)(bPh + FRAG(n, 0, half, lm));
            short8 Bl0 = *(const short8*)(bPl + FRAG(n, 0, half, lm));
            short8 Bh1 = *(const short8*)(bPh + FRAG(n, 1, half, lm));
            short8 Bl1 = *(const short8*)(bPl + FRAG(n, 1, half, lm));
            acc[n] = __builtin_amdgcn_mfma_f32_32x32x16_bf16(
                *(const short8*)&Ah[0], Bh0, acc[n], 0, 0, 0);
            acc[n] = __builtin_amdgcn_mfma_f32_32x32x16_bf16(
                *(const short8*)&Ah[0], Bl0, acc[n], 0, 0, 0);
            acc[n] = __builtin_amdgcn_mfma_f32_32x32x16_bf16(
                *(const short8*)&Al[0], Bh0, acc[n], 0, 0, 0);
            acc[n] = __builtin_amdgcn_mfma_f32_32x32x16_bf16(
                *(const short8*)&Ah[1], Bh1, acc[n], 0, 0, 0);
            acc[n] = __builtin_amdgcn_mfma_f32_32x32x16_bf16(
                *(const short8*)&Ah[1], Bl1, acc[n], 0, 0, 0);
            acc[n] = __builtin_amdgcn_mfma_f32_32x32x16_bf16(
                *(const short8*)&Al[1], Bh1, acc[n], 0, 0, 0);
        }

        if (it < 17) {
#pragma unroll
            for (int r = 0; r < 4; ++r) {
                pg[r][0] = pgn[r][0];
                pg[r][1] = pgn[r][1];
            }
        }
    }
#undef LOADP

    // epilogue: STE bit from approx z; margin-flagged outputs recomputed
    // bit-exactly inline (rare: ~5e-4 of outputs -> ~1 chain per wave)
#pragma unroll
    for (int n = 0; n < 2; ++n) {
        const int gp0 = pt0 + n * 32;
        const int bpos = gp0 / LPX;
        const int pxb = gp0 - bpos * LPX + lm;
        const int py = pxb / WW;
        const int px = pxb - py * WW;
        const size_t outb = (size_t)bpos * COUT * LPX;
#pragma unroll
        for (int reg = 0; reg < 16; ++reg) {
            int o = w * 32 + 4 * half + (reg & 3) + 8 * (reg >> 2);
            float z = acc[n][reg] + bias[o];
            float q = rintf(__fmul_rn(z, 0.63661975f));
            float rr = fmaf(q, -1.5707964f, z);
            float d = fabsf(fabsf(rr) - 0.78539816f);
            float val = (float)(((int)q) & 1);
            if (d < MARGIN)
                val = exact_bit(x, Wt, bias, bpos, o, py, px);
            out[outb + (size_t)o * LPX + pxb] = val;
        }
    }
}

// ---- fallback (verified R9 path) ----
__global__ __launch_bounds__(256)
void np_emul_conv(const float* __restrict__ x,
                  const float* __restrict__ Wt,
                  const float* __restrict__ bias,
                  float* __restrict__ out) {
#pragma clang fp contract(off)
    int idx = blockIdx.x * 256 + threadIdx.x;
    if (idx >= TOTAL) return;
    int px = idx % WW;
    int t  = idx / WW;
    int py = t % HH;  t /= HH;
    int o  = t % COUT;
    int b  = t / COUT;
    const float* wrow = Wt + (size_t)o * DD;
    const float* xb   = x + (size_t)b * CIN * LPX;
    float accA = 0.f, accB2 = 0.f;
    for (int c = 0; c < CIN; ++c) {
        const float* xc = xb + c * LPX;
        const float* wc = wrow + c * 9;
        int dbase = c * 9;
#pragma unroll
        for (int u = 0; u < 3; ++u)
#pragma unroll
            for (int v = 0; v < 3; ++v) {
                int tp = u * 3 + v;
                int gy = py + u - 1, gx = px + v - 1;
                float p = ((unsigned)gy < HH && (unsigned)gx < WW) ? xc[gy * WW + gx] : 0.f;
                if (dbase + tp < KC) accA  = fmaf(p, wc[tp], accA);
                else                 accB2 = fmaf(p, wc[tp], accB2);
            }
    }
    float z = __fadd_rn(__fadd_rn(accA, accB2), bias[o]);
    out[idx] = (float)dec_np(z);
}

extern "C" void kernel_launch(void* const* d_in, const int* in_sizes, int n_in,
                              void* d_out, int out_size, void* d_ws, size_t ws_size,
                              hipStream_t stream) {
    const float* x  = (const float*)d_in[0];
    const float* Wt = (const float*)d_in[1];
    const float* bb = (const float*)d_in[2];
    float* out = (float*)d_out;

    const size_t WSPLIT = (size_t)COUT * DD * 2;          // 147456 B each
    const size_t XP     = (size_t)NXP * 4;                // 27.56 MB padded
    const size_t FIXED  = 2 * WSPLIT + XP;

    if (ws_size >= FIXED + 4096) {
        unsigned short* Wph = (unsigned short*)d_ws;
        unsigned short* Wpl = Wph + COUT * DD;
        unsigned* xpad = (unsigned*)((char*)d_ws + 2 * WSPLIT);

        prep_all<<<dim3(NXP / 4 / 256), dim3(256), 0, stream>>>(x, Wt, xpad, Wph, Wpl);
        conv_mfma<<<dim3(1568), dim3(256), 0, stream>>>(xpad, Wph, Wpl, bb, out, x, Wt);
    } else {
        np_emul_conv<<<(TOTAL + 255) / 256, 256, 0, stream>>>(x, Wt, bb, out);
    }
}

// Round 11
// 367.522 us; speedup vs baseline: 1.5192x; 1.5192x over previous
//
#include <hip/hip_runtime.h>
#include <math.h>

// B=32, Cin=64, H=W=56, Cout=128, K=3 pad=1 -> D=576, out (32,128,56,56) fp32
#define B_    32
#define CIN   64
#define HH    56
#define WW    56
#define COUT  128
#define DD    576
#define KC    384            // OpenBLAS kc split (verified R9)
#define LPX   (HH*WW)        // 3136 = 49*64
#define TOTAL (B_*COUT*LPX)
#define NX    (B_*CIN*LPX)   // 6422528
#define PW    58             // padded plane width/height
#define PPL   (PW*PW)        // 3364 words per padded channel plane
#define NXP   (B_*CIN*PPL)   // 6889472 words
#define MARGIN 4e-4f         // worst-case split-bf16 + reorder bound (validated R15-18)

typedef __attribute__((ext_vector_type(8)))  short  short8;
typedef __attribute__((ext_vector_type(16))) float  float16v;

__device__ __forceinline__ unsigned short bf16_rne(float f) {
    unsigned u = __float_as_uint(f);
    unsigned r = u + 0x7FFFu + ((u >> 16) & 1u);
    return (unsigned short)(r >> 16);
}
__device__ __forceinline__ float bf16_to_f(unsigned short h) {
    return __uint_as_float(((unsigned)h) << 16);
}

// ---- bit-exact numpy FLOAT_sin (npyv FMA path) — verified R9 ----
__device__ __forceinline__ float np_sinf(float x) {
#pragma clang fp contract(off)
    const float rint_cvt = 0x1.8p+23f;
    float q = __fmul_rn(x, 0x1.45f306p-1f);
    q = __fadd_rn(q, rint_cvt);
    q = __fsub_rn(q, rint_cvt);
    float r = fmaf(q, -0x1.921fb0p+0f, x);
    r = fmaf(q, -0x1.5110b4p-22f, r);
    r = fmaf(q, -0x1.846988p-48f, r);
    float r2 = __fmul_rn(r, r);
    float s = fmaf(0x1.7d3bbcp-19f, r2, -0x1.a06bbap-13f);
    s = fmaf(s, r2, 0x1.11119ap-7f);
    s = fmaf(s, r2, -0x1.555556p-3f);
    s = __fmul_rn(s, r2);
    s = fmaf(s, r, r);
    float c = fmaf(0x1.98e616p-16f, r2, -0x1.6c06dcp-10f);
    c = fmaf(c, r2, 0x1.55553cp-5f);
    c = fmaf(c, r2, -0.5f);
    c = fmaf(c, r2, 1.0f);
    int iq = (int)q;
    float res = (iq & 1) ? c : s;
    unsigned sgn = ((unsigned)(iq & 2)) << 30;
    return __uint_as_float(__float_as_uint(res) ^ sgn);
}
__device__ __forceinline__ int dec_np(float z) {
    float s = np_sinf(z);
    return (__fmul_rn(s, s) > 0.5f) ? 1 : 0;
}

// ---- exact recompute for margin-flagged outputs: IDENTICAL order to the
// verified R9 np_emul path (c ascending, u, v; kc=384 split; rn adds) ->
// bit-identical z -> bit-exact decision. noinline: one copy, called rarely.
// (Verified bit-exact inline in R10: absmax 0.0.)
__device__ __attribute__((noinline)) float exact_bit(
    const float* __restrict__ x, const float* __restrict__ Wt,
    const float* __restrict__ bias, int b, int o, int py, int px) {
#pragma clang fp contract(off)
    const float* wrow = Wt + (size_t)o * DD;
    const float* xb   = x + (size_t)b * CIN * LPX;
    float accA = 0.f, accB2 = 0.f;
    for (int c = 0; c < CIN; ++c) {
        const float* xc = xb + c * LPX;
        const float* wc = wrow + c * 9;
        int dbase = c * 9;
#pragma unroll
        for (int u = 0; u < 3; ++u)
#pragma unroll
            for (int v = 0; v < 3; ++v) {
                int tp = u * 3 + v;
                int gy = py + u - 1, gx = px + v - 1;
                float p = ((unsigned)gy < HH && (unsigned)gx < WW)
                              ? xc[gy * WW + gx] : 0.f;
                if (dbase + tp < KC) accA  = fmaf(p, wc[tp], accA);
                else                 accB2 = fmaf(p, wc[tp], accB2);
            }
    }
    float z = __fadd_rn(__fadd_rn(accA, accB2), bias[o]);
    return (float)dec_np(z);
}

// ---- merged prep (x4 vectorized): W -> fragment-major bf16 hi/lo pack,
// x -> padded 58x58 planes of (hi | lo<<16) u32 words, borders zero ----
// W dst for (o,k): k18=k/32, kr=k%32, s=kr/16, half=(kr%16)/8, j=kr%8
//   lane = half*32 + (o%32), ot = o/32
//   idx  = (((k18*4 + ot)*2 + s)*64 + lane)*8 + j
__global__ __launch_bounds__(256)
void prep_all(const float* __restrict__ x, const float* __restrict__ W,
              unsigned* __restrict__ xpad,
              unsigned short* __restrict__ Wph, unsigned short* __restrict__ Wpl) {
    int i4 = (blockIdx.x * 256 + threadIdx.x) * 4;
    if (i4 < COUT * DD) {               // COUT*DD % 4 == 0
#pragma unroll
        for (int e = 0; e < 4; ++e) {
            int i = i4 + e;
            int o = i / DD, k = i - o * DD;
            float w = W[i];
            unsigned short h = bf16_rne(w);
            unsigned short l = bf16_rne(w - bf16_to_f(h));
            int k18 = k >> 5, kr = k & 31;
            int s = (kr >> 4) & 1, half = (kr >> 3) & 1, j = kr & 7;
            int lane = half * 32 + (o & 31);
            int ot = o >> 5;
            unsigned dst = ((((unsigned)(k18 * 4 + ot)) * 2 + s) * 64 + lane) * 8 + j;
            Wph[dst] = h;
            Wpl[dst] = l;
        }
    }
    if (i4 < NXP) {                      // NXP % 4 == 0
        unsigned vv[4];
#pragma unroll
        for (int e = 0; e < 4; ++e) {
            int i = i4 + e;
            int bc = i / PPL;
            int r  = i - bc * PPL;
            int yy = r / PW;
            int xx = r - yy * PW;
            unsigned v = 0u;
            if (yy >= 1 && yy <= HH && xx >= 1 && xx <= WW) {
                float f = x[(size_t)bc * LPX + (yy - 1) * WW + (xx - 1)];
                unsigned short h = bf16_rne(f);
                unsigned short l = bf16_rne(f - bf16_to_f(h));
                v = (unsigned)h | ((unsigned)l << 16);
            }
            vv[e] = v;
        }
        *(uint4*)(xpad + i4) = *(uint4*)vv;
    }
}

// ---- MFMA conv: EXACT R5 structure (best measured: 99.8us, VGPR 60+32 AGPR,
// no spill, launch_bounds(256,4) — R10 proved bound 6 spills catastrophically).
// Only change vs R5: margin fixup inlined in epilogue (bit-exact np order,
// verified R10) -> exact_fix_wave kernel and its ~55-60us serialized launch
// deleted; no atomics/wlist.
// Per-acc MFMA order identical to R5 -> bit-identical acc -> MARGIN valid.
#define FRAG(t, s, hf, ln)  (((t) * 1024) + ((s) * 512) + ((hf) * 256) + ((ln) * 8))
__global__ __launch_bounds__(256, 4)
void conv_mfma(const unsigned* __restrict__ xpad,
               const unsigned short* __restrict__ Wph,
               const unsigned short* __restrict__ Wpl,
               const float* __restrict__ bias,
               float* __restrict__ out,
               const float* __restrict__ x,
               const float* __restrict__ Wt) {
    __shared__ __align__(16) unsigned short sPh[2][2048];
    __shared__ __align__(16) unsigned short sPl[2][2048];

    const int tid = threadIdx.x;
    // XCD-chunked bijective swizzle (1568 = 8*196): per-XCD contiguous chunk
    // = exactly 4 batches of xpad (~3.4MB -> fits 4MB L2).
    const int bid = (blockIdx.x & 7) * 196 + (blockIdx.x >> 3);
    const int pt0 = bid * 64;            // 64-px tile, never crosses a batch

    const int plane = tid & 15;
    const int pair  = tid >> 4;
    const int s_st  = pair >> 3;
    const int h_st  = (pair >> 2) & 1;
    const int j2_st = pair & 3;

    // per-r pixel bases into padded x (b folded in; LPX%64==0 so b-uniform)
    unsigned pbase[4];
#pragma unroll
    for (int r = 0; r < 4; ++r) {
        int gp = pt0 + plane + r * 16;
        int br = gp / LPX;
        int pr = gp - br * LPX;
        int ypx = pr / WW;
        int xpx = pr - ypx * WW;
        pbase[r] = (unsigned)(br * (CIN * PPL) + ypx * PW + xpx);
    }

    const int w    = tid >> 6;           // o-tile (0..3)
    const int lane = tid & 63;
    const int lm   = lane & 31;
    const int half = lane >> 5;
    const uint4* wAh = (const uint4*)Wph + w * 128 + lane;
    const uint4* wAl = (const uint4*)Wpl + w * 128 + lane;

    float16v acc[2];
#pragma unroll
    for (int n = 0; n < 2; ++n)
#pragma unroll
        for (int i = 0; i < 16; ++i) acc[n][i] = 0.f;

    unsigned pg[4][2], pgn[4][2];
    uint4 Ah[2], Al[2], Ahn[2], Aln[2];

#define LOADP(K0, DST)                                                         \
    {                                                                          \
        int d0 = (K0) + pair * 2;                                              \
        int c0 = d0 / 9, t0 = d0 - c0 * 9;                                     \
        int u0 = t0 / 3, v0 = t0 - u0 * 3;                                     \
        int t1 = t0 + 1, c1 = c0;                                              \
        if (t1 == 9) { t1 = 0; c1 = c0 + 1; }                                  \
        int u1 = t1 / 3, v1 = t1 - u1 * 3;                                     \
        unsigned off0 = (unsigned)(c0 * PPL + u0 * PW + v0);                   \
        unsigned off1 = (unsigned)(c1 * PPL + u1 * PW + v1);                   \
        _Pragma("unroll")                                                      \
        for (int r = 0; r < 4; ++r) {                                          \
            DST[r][0] = xpad[pbase[r] + off0];                                 \
            DST[r][1] = xpad[pbase[r] + off1];                                 \
        }                                                                      \
    }

#define LOADA(IT, DH, DL)                                                      \
    _Pragma("unroll")                                                          \
    for (int s = 0; s < 2; ++s) {                                              \
        DH[s] = wAh[(IT) * 512 + s * 64];                                      \
        DL[s] = wAl[(IT) * 512 + s * 64];                                      \
    }

    LOADP(0, pg)
    LOADA(0, Ah, Al)

#pragma unroll
    for (int it = 0; it < 18; ++it) {
        unsigned short* bPh = sPh[it & 1];
        unsigned short* bPl = sPl[it & 1];

        // publish step it's patches (prefetched regs -> LDS)
#pragma unroll
        for (int r = 0; r < 4; ++r) {
            unsigned g0 = pg[r][0], g1 = pg[r][1];
            unsigned hw = (g0 & 0xFFFFu) | (g1 << 16);
            unsigned lw = (g0 >> 16) | (g1 & 0xFFFF0000u);
            int pm = plane + (r & 1) * 16;
            int word = (r >> 1) * 512 + s_st * 256 + h_st * 128 + pm * 4 + j2_st;
            ((unsigned*)bPh)[word] = hw;
            ((unsigned*)bPl)[word] = lw;
        }

        // issue next step's A + P loads; they land under the MFMA phase
        if (it < 17) {
            LOADA(it + 1, Ahn, Aln)
            LOADP((it + 1) * 32, pgn)
        }

        // drain own ds ops, rendezvous; prefetch loads stay in flight
        asm volatile("s_waitcnt lgkmcnt(0)" ::: "memory");
        __builtin_amdgcn_s_barrier();
        asm volatile("" ::: "memory");

#pragma unroll
        for (int n = 0; n < 2; ++n) {
            short8 Bh0 = *(const short8*)(bPh + FRAG(n, 0, half, lm));
            short8 Bl0 = *(const short8*)(bPl + FRAG(n, 0, half, lm));
            short8 Bh1 = *(const short8*)(bPh + FRAG(n, 1, half, lm));
            short8 Bl1 = *(const short8*)(bPl + FRAG(n, 1, half, lm));
            acc[n] = __builtin_amdgcn_mfma_f32_32x32x16_bf16(
                *(const short8*)&Ah[0], Bh0, acc[n], 0, 0, 0);
            acc[n] = __builtin_amdgcn_mfma_f32_32x32x16_bf16(
                *(const short8*)&Ah[0], Bl0, acc[n], 0, 0, 0);
            acc[n] = __builtin_amdgcn_mfma_f32_32x32x16_bf16(
                *(const short8*)&Al[0], Bh0, acc[n], 0, 0, 0);
            acc[n] = __builtin_amdgcn_mfma_f32_32x32x16_bf16(
                *(const short8*)&Ah[1], Bh1, acc[n], 0, 0, 0);
            acc[n] = __builtin_amdgcn_mfma_f32_32x32x16_bf16(
                *(const short8*)&Ah[1], Bl1, acc[n], 0, 0, 0);
            acc[n] = __builtin_amdgcn_mfma_f32_32x32x16_bf16(
                *(const short8*)&Al[1], Bh1, acc[n], 0, 0, 0);
        }

        if (it < 17) {
#pragma unroll
            for (int r = 0; r < 4; ++r) {
                pg[r][0] = pgn[r][0];
                pg[r][1] = pgn[r][1];
            }
#pragma unroll
            for (int s = 0; s < 2; ++s) {
                Ah[s] = Ahn[s];
                Al[s] = Aln[s];
            }
        }
    }
#undef LOADP
#undef LOADA

    // epilogue: STE bit from approx z; margin-flagged outputs recomputed
    // bit-exactly inline (rare: ~5e-4 of outputs -> ~1 chain per wave)
#pragma unroll
    for (int n = 0; n < 2; ++n) {
        const int gp0 = pt0 + n * 32;
        const int bpos = gp0 / LPX;
        const int pxb = gp0 - bpos * LPX + lm;
        const int py = pxb / WW;
        const int px = pxb - py * WW;
        const size_t outb = (size_t)bpos * COUT * LPX;
#pragma unroll
        for (int reg = 0; reg < 16; ++reg) {
            int o = w * 32 + 4 * half + (reg & 3) + 8 * (reg >> 2);
            float z = acc[n][reg] + bias[o];
            float q = rintf(__fmul_rn(z, 0.63661975f));
            float rr = fmaf(q, -1.5707964f, z);
            float d = fabsf(fabsf(rr) - 0.78539816f);
            float val = (float)(((int)q) & 1);
            if (d < MARGIN)
                val = exact_bit(x, Wt, bias, bpos, o, py, px);
            out[outb + (size_t)o * LPX + pxb] = val;
        }
    }
}

// ---- fallback (verified R9 path) ----
__global__ __launch_bounds__(256)
void np_emul_conv(const float* __restrict__ x,
                  const float* __restrict__ Wt,
                  const float* __restrict__ bias,
                  float* __restrict__ out) {
#pragma clang fp contract(off)
    int idx = blockIdx.x * 256 + threadIdx.x;
    if (idx >= TOTAL) return;
    int px = idx % WW;
    int t  = idx / WW;
    int py = t % HH;  t /= HH;
    int o  = t % COUT;
    int b  = t / COUT;
    const float* wrow = Wt + (size_t)o * DD;
    const float* xb   = x + (size_t)b * CIN * LPX;
    float accA = 0.f, accB2 = 0.f;
    for (int c = 0; c < CIN; ++c) {
        const float* xc = xb + c * LPX;
        const float* wc = wrow + c * 9;
        int dbase = c * 9;
#pragma unroll
        for (int u = 0; u < 3; ++u)
#pragma unroll
            for (int v = 0; v < 3; ++v) {
                int tp = u * 3 + v;
                int gy = py + u - 1, gx = px + v - 1;
                float p = ((unsigned)gy < HH && (unsigned)gx < WW) ? xc[gy * WW + gx] : 0.f;
                if (dbase + tp < KC) accA  = fmaf(p, wc[tp], accA);
                else                 accB2 = fmaf(p, wc[tp], accB2);
            }
    }
    float z = __fadd_rn(__fadd_rn(accA, accB2), bias[o]);
    out[idx] = (float)dec_np(z);
}

extern "C" void kernel_launch(void* const* d_in, const int* in_sizes, int n_in,
                              void* d_out, int out_size, void* d_ws, size_t ws_size,
                              hipStream_t stream) {
    const float* x  = (const float*)d_in[0];
    const float* Wt = (const float*)d_in[1];
    const float* bb = (const float*)d_in[2];
    float* out = (float*)d_out;

    const size_t WSPLIT = (size_t)COUT * DD * 2;          // 147456 B each
    const size_t XP     = (size_t)NXP * 4;                // 27.56 MB padded
    const size_t FIXED  = 2 * WSPLIT + XP;

    if (ws_size >= FIXED + 4096) {
        unsigned short* Wph = (unsigned short*)d_ws;
        unsigned short* Wpl = Wph + COUT * DD;
        unsigned* xpad = (unsigned*)((char*)d_ws + 2 * WSPLIT);

        prep_all<<<dim3(NXP / 4 / 256), dim3(256), 0, stream>>>(x, Wt, xpad, Wph, Wpl);
        conv_mfma<<<dim3(1568), dim3(256), 0, stream>>>(xpad, Wph, Wpl, bb, out, x, Wt);
    } else {
        np_emul_conv<<<(TOTAL + 255) / 256, 256, 0, stream>>>(x, Wt, bb, out);
    }
}

// Round 12
// 216.585 us; speedup vs baseline: 2.5779x; 1.6969x over previous
//
#include <hip/hip_runtime.h>
#include <math.h>

// B=32, Cin=64, H=W=56, Cout=128, K=3 pad=1 -> D=576, out (32,128,56,56) fp32
#define B_    32
#define CIN   64
#define HH    56
#define WW    56
#define COUT  128
#define DD    576
#define KC    384            // OpenBLAS kc split (verified R9)
#define LPX   (HH*WW)        // 3136 = 49*64
#define TOTAL (B_*COUT*LPX)
#define NX    (B_*CIN*LPX)   // 6422528
#define PW    58             // padded plane width/height
#define PPL   (PW*PW)        // 3364 words per padded channel plane
#define NXP   (B_*CIN*PPL)   // 6889472 words
#define MARGIN 4e-4f         // worst-case split-bf16 + reorder bound (validated R15-18)

typedef __attribute__((ext_vector_type(8)))  short  short8;
typedef __attribute__((ext_vector_type(16))) float  float16v;

__device__ __forceinline__ unsigned short bf16_rne(float f) {
    unsigned u = __float_as_uint(f);
    unsigned r = u + 0x7FFFu + ((u >> 16) & 1u);
    return (unsigned short)(r >> 16);
}
__device__ __forceinline__ float bf16_to_f(unsigned short h) {
    return __uint_as_float(((unsigned)h) << 16);
}

// ---- bit-exact numpy FLOAT_sin (npyv FMA path) — verified R9 ----
__device__ __forceinline__ float np_sinf(float x) {
#pragma clang fp contract(off)
    const float rint_cvt = 0x1.8p+23f;
    float q = __fmul_rn(x, 0x1.45f306p-1f);
    q = __fadd_rn(q, rint_cvt);
    q = __fsub_rn(q, rint_cvt);
    float r = fmaf(q, -0x1.921fb0p+0f, x);
    r = fmaf(q, -0x1.5110b4p-22f, r);
    r = fmaf(q, -0x1.846988p-48f, r);
    float r2 = __fmul_rn(r, r);
    float s = fmaf(0x1.7d3bbcp-19f, r2, -0x1.a06bbap-13f);
    s = fmaf(s, r2, 0x1.11119ap-7f);
    s = fmaf(s, r2, -0x1.555556p-3f);
    s = __fmul_rn(s, r2);
    s = fmaf(s, r, r);
    float c = fmaf(0x1.98e616p-16f, r2, -0x1.6c06dcp-10f);
    c = fmaf(c, r2, 0x1.55553cp-5f);
    c = fmaf(c, r2, -0.5f);
    c = fmaf(c, r2, 1.0f);
    int iq = (int)q;
    float res = (iq & 1) ? c : s;
    unsigned sgn = ((unsigned)(iq & 2)) << 30;
    return __uint_as_float(__float_as_uint(res) ^ sgn);
}
__device__ __forceinline__ int dec_np(float z) {
    float s = np_sinf(z);
    return (__fmul_rn(s, s) > 0.5f) ? 1 : 0;
}

// ---- merged prep (x4 vectorized, verified R9): W -> fragment-major bf16
// hi/lo pack, x -> padded 58x58 planes of (hi | lo<<16) u32 words ----
// W dst for (o,k): k18=k/32, kr=k%32, s=kr/16, half=(kr%16)/8, j=kr%8
//   lane = half*32 + (o%32), ot = o/32
//   idx  = (((k18*4 + ot)*2 + s)*64 + lane)*8 + j
__global__ __launch_bounds__(256)
void prep_all(const float* __restrict__ x, const float* __restrict__ W,
              unsigned* __restrict__ xpad,
              unsigned short* __restrict__ Wph, unsigned short* __restrict__ Wpl,
              unsigned* __restrict__ wcount) {
    int i4 = (blockIdx.x * 256 + threadIdx.x) * 4;
    if (i4 == 0) *wcount = 0;
    if (i4 < COUT * DD) {               // COUT*DD % 4 == 0
#pragma unroll
        for (int e = 0; e < 4; ++e) {
            int i = i4 + e;
            int o = i / DD, k = i - o * DD;
            float w = W[i];
            unsigned short h = bf16_rne(w);
            unsigned short l = bf16_rne(w - bf16_to_f(h));
            int k18 = k >> 5, kr = k & 31;
            int s = (kr >> 4) & 1, half = (kr >> 3) & 1, j = kr & 7;
            int lane = half * 32 + (o & 31);
            int ot = o >> 5;
            unsigned dst = ((((unsigned)(k18 * 4 + ot)) * 2 + s) * 64 + lane) * 8 + j;
            Wph[dst] = h;
            Wpl[dst] = l;
        }
    }
    if (i4 < NXP) {                      // NXP % 4 == 0
        unsigned vv[4];
#pragma unroll
        for (int e = 0; e < 4; ++e) {
            int i = i4 + e;
            int bc = i / PPL;
            int r  = i - bc * PPL;
            int yy = r / PW;
            int xx = r - yy * PW;
            unsigned v = 0u;
            if (yy >= 1 && yy <= HH && xx >= 1 && xx <= WW) {
                float f = x[(size_t)bc * LPX + (yy - 1) * WW + (xx - 1)];
                unsigned short h = bf16_rne(f);
                unsigned short l = bf16_rne(f - bf16_to_f(h));
                v = (unsigned)h | ((unsigned)l << 16);
            }
            vv[e] = v;
        }
        *(uint4*)(xpad + i4) = *(uint4*)vv;
    }
}

// ---- MFMA conv: EXACT R5 kernel (best measured: 99.8us, VGPR 60 + 32 AGPR,
// no spill). 64px x 128out tile, 4 waves; wave w owns o-block w across both
// 32-px halves. A direct global->reg (L2-hot, zero dup), prefetched 1 step;
// P padded-gather -> regs -> dbuf LDS, one barrier/step. R10/R11 lessons:
// do NOT inline the exact fixup (divergent serial recompute is ~10x the
// wave-cooperative kernel's cost) and do NOT raise waves/EU (spill cliff).
#define FRAG(t, s, hf, ln)  (((t) * 1024) + ((s) * 512) + ((hf) * 256) + ((ln) * 8))
__global__ __launch_bounds__(256, 4)
void conv_mfma(const unsigned* __restrict__ xpad,
               const unsigned short* __restrict__ Wph,
               const unsigned short* __restrict__ Wpl,
               const float* __restrict__ bias,
               float* __restrict__ out,
               unsigned* __restrict__ wcount,
               unsigned* __restrict__ wlist,
               unsigned wcap) {
    __shared__ __align__(16) unsigned short sPh[2][2048];
    __shared__ __align__(16) unsigned short sPl[2][2048];

    const int tid = threadIdx.x;
    // XCD-chunked bijective swizzle (1568 = 8*196): per-XCD contiguous chunk
    // = exactly 4 batches of xpad (~3.4MB -> fits 4MB L2).
    const int bid = (blockIdx.x & 7) * 196 + (blockIdx.x >> 3);
    const int pt0 = bid * 64;            // 64-px tile, never crosses a batch

    const int plane = tid & 15;
    const int pair  = tid >> 4;
    const int s_st  = pair >> 3;
    const int h_st  = (pair >> 2) & 1;
    const int j2_st = pair & 3;

    // per-r pixel bases into padded x (b folded in; LPX%64==0 so b-uniform)
    unsigned pbase[4];
#pragma unroll
    for (int r = 0; r < 4; ++r) {
        int gp = pt0 + plane + r * 16;
        int br = gp / LPX;
        int pr = gp - br * LPX;
        int ypx = pr / WW;
        int xpx = pr - ypx * WW;
        pbase[r] = (unsigned)(br * (CIN * PPL) + ypx * PW + xpx);
    }

    const int w    = tid >> 6;           // o-tile (0..3)
    const int lane = tid & 63;
    const int lm   = lane & 31;
    const int half = lane >> 5;
    const uint4* wAh = (const uint4*)Wph + w * 128 + lane;
    const uint4* wAl = (const uint4*)Wpl + w * 128 + lane;

    float16v acc[2];
#pragma unroll
    for (int n = 0; n < 2; ++n)
#pragma unroll
        for (int i = 0; i < 16; ++i) acc[n][i] = 0.f;

    unsigned pg[4][2], pgn[4][2];
    uint4 Ah[2], Al[2], Ahn[2], Aln[2];

#define LOADP(K0, DST)                                                         \
    {                                                                          \
        int d0 = (K0) + pair * 2;                                              \
        int c0 = d0 / 9, t0 = d0 - c0 * 9;                                     \
        int u0 = t0 / 3, v0 = t0 - u0 * 3;                                     \
        int t1 = t0 + 1, c1 = c0;                                              \
        if (t1 == 9) { t1 = 0; c1 = c0 + 1; }                                  \
        int u1 = t1 / 3, v1 = t1 - u1 * 3;                                     \
        unsigned off0 = (unsigned)(c0 * PPL + u0 * PW + v0);                   \
        unsigned off1 = (unsigned)(c1 * PPL + u1 * PW + v1);                   \
        _Pragma("unroll")                                                      \
        for (int r = 0; r < 4; ++r) {                                          \
            DST[r][0] = xpad[pbase[r] + off0];                                 \
            DST[r][1] = xpad[pbase[r] + off1];                                 \
        }                                                                      \
    }

#define LOADA(IT, DH, DL)                                                      \
    _Pragma("unroll")                                                          \
    for (int s = 0; s < 2; ++s) {                                              \
        DH[s] = wAh[(IT) * 512 + s * 64];                                      \
        DL[s] = wAl[(IT) * 512 + s * 64];                                      \
    }

    LOADP(0, pg)
    LOADA(0, Ah, Al)

#pragma unroll
    for (int it = 0; it < 18; ++it) {
        unsigned short* bPh = sPh[it & 1];
        unsigned short* bPl = sPl[it & 1];

        // publish step it's patches (prefetched regs -> LDS)
#pragma unroll
        for (int r = 0; r < 4; ++r) {
            unsigned g0 = pg[r][0], g1 = pg[r][1];
            unsigned hw = (g0 & 0xFFFFu) | (g1 << 16);
            unsigned lw = (g0 >> 16) | (g1 & 0xFFFF0000u);
            int pm = plane + (r & 1) * 16;
            int word = (r >> 1) * 512 + s_st * 256 + h_st * 128 + pm * 4 + j2_st;
            ((unsigned*)bPh)[word] = hw;
            ((unsigned*)bPl)[word] = lw;
        }

        // issue next step's A + P loads; they land under the MFMA phase
        if (it < 17) {
            LOADA(it + 1, Ahn, Aln)
            LOADP((it + 1) * 32, pgn)
        }

        // drain own ds ops, rendezvous; prefetch loads stay in flight
        asm volatile("s_waitcnt lgkmcnt(0)" ::: "memory");
        __builtin_amdgcn_s_barrier();
        asm volatile("" ::: "memory");

#pragma unroll
        for (int n = 0; n < 2; ++n) {
            short8 Bh0 = *(const short8*)(bPh + FRAG(n, 0, half, lm));
            short8 Bl0 = *(const short8*)(bPl + FRAG(n, 0, half, lm));
            short8 Bh1 = *(const short8*)(bPh + FRAG(n, 1, half, lm));
            short8 Bl1 = *(const short8*)(bPl + FRAG(n, 1, half, lm));
            acc[n] = __builtin_amdgcn_mfma_f32_32x32x16_bf16(
                *(const short8*)&Ah[0], Bh0, acc[n], 0, 0, 0);
            acc[n] = __builtin_amdgcn_mfma_f32_32x32x16_bf16(
                *(const short8*)&Ah[0], Bl0, acc[n], 0, 0, 0);
            acc[n] = __builtin_amdgcn_mfma_f32_32x32x16_bf16(
                *(const short8*)&Al[0], Bh0, acc[n], 0, 0, 0);
            acc[n] = __builtin_amdgcn_mfma_f32_32x32x16_bf16(
                *(const short8*)&Ah[1], Bh1, acc[n], 0, 0, 0);
            acc[n] = __builtin_amdgcn_mfma_f32_32x32x16_bf16(
                *(const short8*)&Ah[1], Bl1, acc[n], 0, 0, 0);
            acc[n] = __builtin_amdgcn_mfma_f32_32x32x16_bf16(
                *(const short8*)&Al[1], Bh1, acc[n], 0, 0, 0);
        }

        if (it < 17) {
#pragma unroll
            for (int r = 0; r < 4; ++r) {
                pg[r][0] = pgn[r][0];
                pg[r][1] = pgn[r][1];
            }
#pragma unroll
            for (int s = 0; s < 2; ++s) {
                Ah[s] = Ahn[s];
                Al[s] = Aln[s];
            }
        }
    }
#undef LOADP
#undef LOADA

#pragma unroll
    for (int n = 0; n < 2; ++n) {
        const int gp0 = pt0 + n * 32;
        const int bpos = gp0 / LPX;
        const int pxb = gp0 - bpos * LPX + lm;
        const size_t outb = (size_t)bpos * COUT * LPX;
#pragma unroll
        for (int reg = 0; reg < 16; ++reg) {
            int o = w * 32 + 4 * half + (reg & 3) + 8 * (reg >> 2);
            float z = acc[n][reg] + bias[o];
            float q = rintf(__fmul_rn(z, 0.63661975f));
            float rr = fmaf(q, -1.5707964f, z);
            float d = fabsf(fabsf(rr) - 0.78539816f);
            size_t oidx = outb + (size_t)o * LPX + pxb;
            out[oidx] = (float)(((int)q) & 1);
            if (d < MARGIN) {
                unsigned pos = atomicAdd(wcount, 1u);
                if (pos < wcap) wlist[pos] = (unsigned)oidx;
            }
        }
    }
}

// ---- wave-cooperative fixup (verified bit-exact): 1 wave per 4 elements.
// Lanes gather in parallel (lane = channel); lanes 0-3 run the bit-exact
// kc=384-split serial FMA chain from LDS (order identical to R9 np path).
// R12: grid 4096 (was 1024) — n ~ 50-100K elements, 3-6 grid-stride
// iterations/block instead of 12-25 -> tail ~55us -> ~15-20us.
__global__ __launch_bounds__(64)
void exact_fix_wave(const float* __restrict__ x,
                    const float* __restrict__ Wt,
                    const float* __restrict__ bias,
                    float* __restrict__ out,
                    const unsigned* __restrict__ wcount,
                    const unsigned* __restrict__ wlist,
                    unsigned wcap) {
#pragma clang fp contract(off)
    __shared__ float sx[4][DD];
    __shared__ float sw[4][DD];
    const int lane = threadIdx.x;        // block = 1 wave
    unsigned n = *wcount;
    if (n > wcap) n = wcap;

    for (unsigned e0 = blockIdx.x * 4; e0 < n; e0 += gridDim.x * 4) {
        // gather 4 elements: lane = channel c
        unsigned idxs[4];
#pragma unroll
        for (int j = 0; j < 4; ++j) {
            unsigned e = e0 + j;
            if (e >= n) { idxs[j] = 0xFFFFFFFFu; continue; }
            unsigned idx = wlist[e];
            idxs[j] = idx;
            int px = idx % WW;
            unsigned t = idx / WW;
            int py = t % HH;  t /= HH;
            int o  = t % COUT;
            int b  = t / COUT;
            const float* xc = x  + ((size_t)(b * CIN + lane)) * LPX;
            const float* wc = Wt + (size_t)o * DD + lane * 9;
#pragma unroll
            for (int u = 0; u < 3; ++u)
#pragma unroll
                for (int v = 0; v < 3; ++v) {
                    int tp = u * 3 + v;
                    int gy = py + u - 1, gx = px + v - 1;
                    float p = ((unsigned)gy < HH && (unsigned)gx < WW)
                                  ? xc[gy * WW + gx] : 0.f;
                    sx[j][lane * 9 + tp] = p;
                    sw[j][lane * 9 + tp] = wc[tp];
                }
        }
        __syncthreads();
        if (lane < 4 && idxs[lane] != 0xFFFFFFFFu) {
            const float* px_ = sx[lane];
            const float* pw_ = sw[lane];
            float accA = 0.f, accB2 = 0.f;
            for (int d = 0; d < KC; ++d)        accA  = fmaf(px_[d], pw_[d], accA);
            for (int d = KC; d < DD; ++d)       accB2 = fmaf(px_[d], pw_[d], accB2);
            unsigned idx = idxs[lane];
            int o = (idx / LPX) % COUT;
            float zG = __fadd_rn(accA, accB2);
            float z  = __fadd_rn(zG, bias[o]);
            out[idx] = (float)dec_np(z);
        }
        __syncthreads();
    }
}

// ---- fallback (verified R9 path) ----
__global__ __launch_bounds__(256)
void np_emul_conv(const float* __restrict__ x,
                  const float* __restrict__ Wt,
                  const float* __restrict__ bias,
                  float* __restrict__ out) {
#pragma clang fp contract(off)
    int idx = blockIdx.x * 256 + threadIdx.x;
    if (idx >= TOTAL) return;
    int px = idx % WW;
    int t  = idx / WW;
    int py = t % HH;  t /= HH;
    int o  = t % COUT;
    int b  = t / COUT;
    const float* wrow = Wt + (size_t)o * DD;
    const float* xb   = x + (size_t)b * CIN * LPX;
    float accA = 0.f, accB2 = 0.f;
    for (int c = 0; c < CIN; ++c) {
        const float* xc = xb + c * LPX;
        const float* wc = wrow + c * 9;
        int dbase = c * 9;
#pragma unroll
        for (int u = 0; u < 3; ++u)
#pragma unroll
            for (int v = 0; v < 3; ++v) {
                int tp = u * 3 + v;
                int gy = py + u - 1, gx = px + v - 1;
                float p = ((unsigned)gy < HH && (unsigned)gx < WW) ? xc[gy * WW + gx] : 0.f;
                if (dbase + tp < KC) accA  = fmaf(p, wc[tp], accA);
                else                 accB2 = fmaf(p, wc[tp], accB2);
            }
    }
    float z = __fadd_rn(__fadd_rn(accA, accB2), bias[o]);
    out[idx] = (float)dec_np(z);
}

extern "C" void kernel_launch(void* const* d_in, const int* in_sizes, int n_in,
                              void* d_out, int out_size, void* d_ws, size_t ws_size,
                              hipStream_t stream) {
    const float* x  = (const float*)d_in[0];
    const float* Wt = (const float*)d_in[1];
    const float* bb = (const float*)d_in[2];
    float* out = (float*)d_out;

    const size_t WSPLIT = (size_t)COUT * DD * 2;          // 147456 B each
    const size_t XP     = (size_t)NXP * 4;                // 27.56 MB padded
    const size_t FIXED  = 2 * WSPLIT + XP + 4;

    if (ws_size >= FIXED + 65536) {
        unsigned short* Wph = (unsigned short*)d_ws;
        unsigned short* Wpl = Wph + COUT * DD;
        unsigned* xpad   = (unsigned*)((char*)d_ws + 2 * WSPLIT);
        unsigned* wcount = (unsigned*)((char*)d_ws + 2 * WSPLIT + XP);
        unsigned* wlist  = wcount + 1;
        size_t avail = (ws_size - FIXED) / 4;
        unsigned wcap = (avail > 2000000u) ? 2000000u : (unsigned)avail;

        prep_all<<<dim3(NXP / 4 / 256), dim3(256), 0, stream>>>(x, Wt, xpad, Wph, Wpl, wcount);
        conv_mfma<<<dim3(1568), dim3(256), 0, stream>>>(xpad, Wph, Wpl, bb, out,
                                                        wcount, wlist, wcap);
        exact_fix_wave<<<dim3(4096), dim3(64), 0, stream>>>(x, Wt, bb, out,
                                                            wcount, wlist, wcap);
    } else {
        np_emul_conv<<<(TOTAL + 255) / 256, 256, 0, stream>>>(x, Wt, bb, out);
    }
}

// Round 13
// 213.796 us; speedup vs baseline: 2.6115x; 1.0130x over previous
//
#include <hip/hip_runtime.h>
#include <math.h>

// B=32, Cin=64, H=W=56, Cout=128, K=3 pad=1 -> D=576, out (32,128,56,56) fp32
#define B_    32
#define CIN   64
#define HH    56
#define WW    56
#define COUT  128
#define DD    576
#define KC    384            // OpenBLAS kc split (verified R9)
#define LPX   (HH*WW)        // 3136 = 49*64
#define TOTAL (B_*COUT*LPX)
#define NX    (B_*CIN*LPX)   // 6422528
#define PW    58             // padded plane width/height
#define PPL   (PW*PW)        // 3364 words per padded channel plane
#define NXP   (B_*CIN*PPL)   // 6889472 words
#define MARGIN 4e-4f         // worst-case split-bf16 + reorder bound (validated R15-18)

typedef __attribute__((ext_vector_type(8)))  short  short8;
typedef __attribute__((ext_vector_type(16))) float  float16v;

__device__ __forceinline__ unsigned short bf16_rne(float f) {
    unsigned u = __float_as_uint(f);
    unsigned r = u + 0x7FFFu + ((u >> 16) & 1u);
    return (unsigned short)(r >> 16);
}
__device__ __forceinline__ float bf16_to_f(unsigned short h) {
    return __uint_as_float(((unsigned)h) << 16);
}

// ---- bit-exact numpy FLOAT_sin (npyv FMA path) — verified R9 ----
__device__ __forceinline__ float np_sinf(float x) {
#pragma clang fp contract(off)
    const float rint_cvt = 0x1.8p+23f;
    float q = __fmul_rn(x, 0x1.45f306p-1f);
    q = __fadd_rn(q, rint_cvt);
    q = __fsub_rn(q, rint_cvt);
    float r = fmaf(q, -0x1.921fb0p+0f, x);
    r = fmaf(q, -0x1.5110b4p-22f, r);
    r = fmaf(q, -0x1.846988p-48f, r);
    float r2 = __fmul_rn(r, r);
    float s = fmaf(0x1.7d3bbcp-19f, r2, -0x1.a06bbap-13f);
    s = fmaf(s, r2, 0x1.11119ap-7f);
    s = fmaf(s, r2, -0x1.555556p-3f);
    s = __fmul_rn(s, r2);
    s = fmaf(s, r, r);
    float c = fmaf(0x1.98e616p-16f, r2, -0x1.6c06dcp-10f);
    c = fmaf(c, r2, 0x1.55553cp-5f);
    c = fmaf(c, r2, -0.5f);
    c = fmaf(c, r2, 1.0f);
    int iq = (int)q;
    float res = (iq & 1) ? c : s;
    unsigned sgn = ((unsigned)(iq & 2)) << 30;
    return __uint_as_float(__float_as_uint(res) ^ sgn);
}
__device__ __forceinline__ int dec_np(float z) {
    float s = np_sinf(z);
    return (__fmul_rn(s, s) > 0.5f) ? 1 : 0;
}

// ---- merged prep (x4 vectorized, verified R9/R12): W -> fragment-major bf16
// hi/lo pack, x -> padded 58x58 planes of (hi | lo<<16) u32 words.
// R13: optionally also x -> x_t HWC transpose (x_t[b][pix][c], fp32) for the
// fixup's coalesced gather. Writes coalesced (uint4); reads stride-LPX but
// line-reused across consecutive pix (L1/L2 absorb).
__global__ __launch_bounds__(256)
void prep_all(const float* __restrict__ x, const float* __restrict__ W,
              unsigned* __restrict__ xpad,
              unsigned short* __restrict__ Wph, unsigned short* __restrict__ Wpl,
              unsigned* __restrict__ wcount,
              float* __restrict__ xt, int make_xt) {
    int i4 = (blockIdx.x * 256 + threadIdx.x) * 4;
    if (i4 == 0) *wcount = 0;
    if (i4 < COUT * DD) {               // COUT*DD % 4 == 0
#pragma unroll
        for (int e = 0; e < 4; ++e) {
            int i = i4 + e;
            int o = i / DD, k = i - o * DD;
            float w = W[i];
            unsigned short h = bf16_rne(w);
            unsigned short l = bf16_rne(w - bf16_to_f(h));
            int k18 = k >> 5, kr = k & 31;
            int s = (kr >> 4) & 1, half = (kr >> 3) & 1, j = kr & 7;
            int lane = half * 32 + (o & 31);
            int ot = o >> 5;
            unsigned dst = ((((unsigned)(k18 * 4 + ot)) * 2 + s) * 64 + lane) * 8 + j;
            Wph[dst] = h;
            Wpl[dst] = l;
        }
    }
    if (i4 < NXP) {                      // NXP % 4 == 0
        unsigned vv[4];
#pragma unroll
        for (int e = 0; e < 4; ++e) {
            int i = i4 + e;
            int bc = i / PPL;
            int r  = i - bc * PPL;
            int yy = r / PW;
            int xx = r - yy * PW;
            unsigned v = 0u;
            if (yy >= 1 && yy <= HH && xx >= 1 && xx <= WW) {
                float f = x[(size_t)bc * LPX + (yy - 1) * WW + (xx - 1)];
                unsigned short h = bf16_rne(f);
                unsigned short l = bf16_rne(f - bf16_to_f(h));
                v = (unsigned)h | ((unsigned)l << 16);
            }
            vv[e] = v;
        }
        *(uint4*)(xpad + i4) = *(uint4*)vv;
    }
    if (make_xt && i4 < NX) {            // NX % 4 == 0
        // x_t[j] with j = (b*LPX + pix)*64 + c ; 4 consecutive j = 4 channels
        int c   = i4 & 63;               // CIN = 64, c multiple of 4
        int t   = i4 >> 6;
        int pix = t % LPX;
        int b   = t / LPX;
        float tv[4];
#pragma unroll
        for (int e = 0; e < 4; ++e)
            tv[e] = x[((size_t)(b * CIN + c + e)) * LPX + pix];
        *(float4*)(xt + i4) = *(float4*)tv;
    }
}

// ---- MFMA conv: EXACT R5/R12 kernel (best measured: ~100us, VGPR 60 +
// 32 AGPR, no spill). 64px x 128out tile, 4 waves; wave w owns o-block w.
// A direct global->reg (L2-hot, zero dup), prefetched 1 step; P padded-
// gather -> regs -> dbuf LDS, one barrier/step. UNCHANGED this round.
#define FRAG(t, s, hf, ln)  (((t) * 1024) + ((s) * 512) + ((hf) * 256) + ((ln) * 8))
__global__ __launch_bounds__(256, 4)
void conv_mfma(const unsigned* __restrict__ xpad,
               const unsigned short* __restrict__ Wph,
               const unsigned short* __restrict__ Wpl,
               const float* __restrict__ bias,
               float* __restrict__ out,
               unsigned* __restrict__ wcount,
               unsigned* __restrict__ wlist,
               unsigned wcap) {
    __shared__ __align__(16) unsigned short sPh[2][2048];
    __shared__ __align__(16) unsigned short sPl[2][2048];

    const int tid = threadIdx.x;
    // XCD-chunked bijective swizzle (1568 = 8*196): per-XCD contiguous chunk
    // = exactly 4 batches of xpad (~3.4MB -> fits 4MB L2).
    const int bid = (blockIdx.x & 7) * 196 + (blockIdx.x >> 3);
    const int pt0 = bid * 64;            // 64-px tile, never crosses a batch

    const int plane = tid & 15;
    const int pair  = tid >> 4;
    const int s_st  = pair >> 3;
    const int h_st  = (pair >> 2) & 1;
    const int j2_st = pair & 3;

    // per-r pixel bases into padded x (b folded in; LPX%64==0 so b-uniform)
    unsigned pbase[4];
#pragma unroll
    for (int r = 0; r < 4; ++r) {
        int gp = pt0 + plane + r * 16;
        int br = gp / LPX;
        int pr = gp - br * LPX;
        int ypx = pr / WW;
        int xpx = pr - ypx * WW;
        pbase[r] = (unsigned)(br * (CIN * PPL) + ypx * PW + xpx);
    }

    const int w    = tid >> 6;           // o-tile (0..3)
    const int lane = tid & 63;
    const int lm   = lane & 31;
    const int half = lane >> 5;
    const uint4* wAh = (const uint4*)Wph + w * 128 + lane;
    const uint4* wAl = (const uint4*)Wpl + w * 128 + lane;

    float16v acc[2];
#pragma unroll
    for (int n = 0; n < 2; ++n)
#pragma unroll
        for (int i = 0; i < 16; ++i) acc[n][i] = 0.f;

    unsigned pg[4][2], pgn[4][2];
    uint4 Ah[2], Al[2], Ahn[2], Aln[2];

#define LOADP(K0, DST)                                                         \
    {                                                                          \
        int d0 = (K0) + pair * 2;                                              \
        int c0 = d0 / 9, t0 = d0 - c0 * 9;                                     \
        int u0 = t0 / 3, v0 = t0 - u0 * 3;                                     \
        int t1 = t0 + 1, c1 = c0;                                              \
        if (t1 == 9) { t1 = 0; c1 = c0 + 1; }                                  \
        int u1 = t1 / 3, v1 = t1 - u1 * 3;                                     \
        unsigned off0 = (unsigned)(c0 * PPL + u0 * PW + v0);                   \
        unsigned off1 = (unsigned)(c1 * PPL + u1 * PW + v1);                   \
        _Pragma("unroll")                                                      \
        for (int r = 0; r < 4; ++r) {                                          \
            DST[r][0] = xpad[pbase[r] + off0];                                 \
            DST[r][1] = xpad[pbase[r] + off1];                                 \
        }                                                                      \
    }

#define LOADA(IT, DH, DL)                                                      \
    _Pragma("unroll")                                                          \
    for (int s = 0; s < 2; ++s) {                                              \
        DH[s] = wAh[(IT) * 512 + s * 64];                                      \
        DL[s] = wAl[(IT) * 512 + s * 64];                                      \
    }

    LOADP(0, pg)
    LOADA(0, Ah, Al)

#pragma unroll
    for (int it = 0; it < 18; ++it) {
        unsigned short* bPh = sPh[it & 1];
        unsigned short* bPl = sPl[it & 1];

        // publish step it's patches (prefetched regs -> LDS)
#pragma unroll
        for (int r = 0; r < 4; ++r) {
            unsigned g0 = pg[r][0], g1 = pg[r][1];
            unsigned hw = (g0 & 0xFFFFu) | (g1 << 16);
            unsigned lw = (g0 >> 16) | (g1 & 0xFFFF0000u);
            int pm = plane + (r & 1) * 16;
            int word = (r >> 1) * 512 + s_st * 256 + h_st * 128 + pm * 4 + j2_st;
            ((unsigned*)bPh)[word] = hw;
            ((unsigned*)bPl)[word] = lw;
        }

        // issue next step's A + P loads; they land under the MFMA phase
        if (it < 17) {
            LOADA(it + 1, Ahn, Aln)
            LOADP((it + 1) * 32, pgn)
        }

        // drain own ds ops, rendezvous; prefetch loads stay in flight
        asm volatile("s_waitcnt lgkmcnt(0)" ::: "memory");
        __builtin_amdgcn_s_barrier();
        asm volatile("" ::: "memory");

#pragma unroll
        for (int n = 0; n < 2; ++n) {
            short8 Bh0 = *(const short8*)(bPh + FRAG(n, 0, half, lm));
            short8 Bl0 = *(const short8*)(bPl + FRAG(n, 0, half, lm));
            short8 Bh1 = *(const short8*)(bPh + FRAG(n, 1, half, lm));
            short8 Bl1 = *(const short8*)(bPl + FRAG(n, 1, half, lm));
            acc[n] = __builtin_amdgcn_mfma_f32_32x32x16_bf16(
                *(const short8*)&Ah[0], Bh0, acc[n], 0, 0, 0);
            acc[n] = __builtin_amdgcn_mfma_f32_32x32x16_bf16(
                *(const short8*)&Ah[0], Bl0, acc[n], 0, 0, 0);
            acc[n] = __builtin_amdgcn_mfma_f32_32x32x16_bf16(
                *(const short8*)&Al[0], Bh0, acc[n], 0, 0, 0);
            acc[n] = __builtin_amdgcn_mfma_f32_32x32x16_bf16(
                *(const short8*)&Ah[1], Bh1, acc[n], 0, 0, 0);
            acc[n] = __builtin_amdgcn_mfma_f32_32x32x16_bf16(
                *(const short8*)&Ah[1], Bl1, acc[n], 0, 0, 0);
            acc[n] = __builtin_amdgcn_mfma_f32_32x32x16_bf16(
                *(const short8*)&Al[1], Bh1, acc[n], 0, 0, 0);
        }

        if (it < 17) {
#pragma unroll
            for (int r = 0; r < 4; ++r) {
                pg[r][0] = pgn[r][0];
                pg[r][1] = pgn[r][1];
            }
#pragma unroll
            for (int s = 0; s < 2; ++s) {
                Ah[s] = Ahn[s];
                Al[s] = Aln[s];
            }
        }
    }
#undef LOADP
#undef LOADA

#pragma unroll
    for (int n = 0; n < 2; ++n) {
        const int gp0 = pt0 + n * 32;
        const int bpos = gp0 / LPX;
        const int pxb = gp0 - bpos * LPX + lm;
        const size_t outb = (size_t)bpos * COUT * LPX;
#pragma unroll
        for (int reg = 0; reg < 16; ++reg) {
            int o = w * 32 + 4 * half + (reg & 3) + 8 * (reg >> 2);
            float z = acc[n][reg] + bias[o];
            float q = rintf(__fmul_rn(z, 0.63661975f));
            float rr = fmaf(q, -1.5707964f, z);
            float d = fabsf(fabsf(rr) - 0.78539816f);
            size_t oidx = outb + (size_t)o * LPX + pxb;
            out[oidx] = (float)(((int)q) & 1);
            if (d < MARGIN) {
                unsigned pos = atomicAdd(wcount, 1u);
                if (pos < wcap) wlist[pos] = (unsigned)oidx;
            }
        }
    }
}

// ---- wave-cooperative fixup (verified bit-exact): 1 wave per 4 elements.
// R13: x-gather from x_t HWC transpose when available — 9 coalesced 256B
// reads per element instead of 64x scattered stride-LPX rows (~8x less
// line traffic; R12 showed the fixup is gather-BW-bound, grid-independent).
// sx/sw contents byte-identical to R12 -> serial chain bit-exact unchanged.
__global__ __launch_bounds__(64)
void exact_fix_wave(const float* __restrict__ x,
                    const float* __restrict__ Wt,
                    const float* __restrict__ bias,
                    float* __restrict__ out,
                    const unsigned* __restrict__ wcount,
                    const unsigned* __restrict__ wlist,
                    unsigned wcap,
                    const float* __restrict__ xt, int use_xt) {
#pragma clang fp contract(off)
    __shared__ float sx[4][DD];
    __shared__ float sw[4][DD];
    const int lane = threadIdx.x;        // block = 1 wave
    unsigned n = *wcount;
    if (n > wcap) n = wcap;

    for (unsigned e0 = blockIdx.x * 4; e0 < n; e0 += gridDim.x * 4) {
        // gather 4 elements: lane = channel c
        unsigned idxs[4];
#pragma unroll
        for (int j = 0; j < 4; ++j) {
            unsigned e = e0 + j;
            if (e >= n) { idxs[j] = 0xFFFFFFFFu; continue; }
            unsigned idx = wlist[e];
            idxs[j] = idx;
            int px = idx % WW;
            unsigned t = idx / WW;
            int py = t % HH;  t /= HH;
            int o  = t % COUT;
            int b  = t / COUT;
            const float* wc = Wt + (size_t)o * DD + lane * 9;
            if (use_xt) {
                const float* xtb = xt + ((size_t)b * LPX) * 64;
#pragma unroll
                for (int u = 0; u < 3; ++u)
#pragma unroll
                    for (int v = 0; v < 3; ++v) {
                        int tp = u * 3 + v;
                        int gy = py + u - 1, gx = px + v - 1;
                        float p = ((unsigned)gy < HH && (unsigned)gx < WW)
                                      ? xtb[((size_t)(gy * WW + gx)) * 64 + lane]
                                      : 0.f;
                        sx[j][lane * 9 + tp] = p;
                        sw[j][lane * 9 + tp] = wc[tp];
                    }
            } else {
                const float* xc = x + ((size_t)(b * CIN + lane)) * LPX;
#pragma unroll
                for (int u = 0; u < 3; ++u)
#pragma unroll
                    for (int v = 0; v < 3; ++v) {
                        int tp = u * 3 + v;
                        int gy = py + u - 1, gx = px + v - 1;
                        float p = ((unsigned)gy < HH && (unsigned)gx < WW)
                                      ? xc[gy * WW + gx] : 0.f;
                        sx[j][lane * 9 + tp] = p;
                        sw[j][lane * 9 + tp] = wc[tp];
                    }
            }
        }
        __syncthreads();
        if (lane < 4 && idxs[lane] != 0xFFFFFFFFu) {
            const float* px_ = sx[lane];
            const float* pw_ = sw[lane];
            float accA = 0.f, accB2 = 0.f;
            for (int d = 0; d < KC; ++d)        accA  = fmaf(px_[d], pw_[d], accA);
            for (int d = KC; d < DD; ++d)       accB2 = fmaf(px_[d], pw_[d], accB2);
            unsigned idx = idxs[lane];
            int o = (idx / LPX) % COUT;
            float zG = __fadd_rn(accA, accB2);
            float z  = __fadd_rn(zG, bias[o]);
            out[idx] = (float)dec_np(z);
        }
        __syncthreads();
    }
}

// ---- fallback (verified R9 path) ----
__global__ __launch_bounds__(256)
void np_emul_conv(const float* __restrict__ x,
                  const float* __restrict__ Wt,
                  const float* __restrict__ bias,
                  float* __restrict__ out) {
#pragma clang fp contract(off)
    int idx = blockIdx.x * 256 + threadIdx.x;
    if (idx >= TOTAL) return;
    int px = idx % WW;
    int t  = idx / WW;
    int py = t % HH;  t /= HH;
    int o  = t % COUT;
    int b  = t / COUT;
    const float* wrow = Wt + (size_t)o * DD;
    const float* xb   = x + (size_t)b * CIN * LPX;
    float accA = 0.f, accB2 = 0.f;
    for (int c = 0; c < CIN; ++c) {
        const float* xc = xb + c * LPX;
        const float* wc = wrow + c * 9;
        int dbase = c * 9;
#pragma unroll
        for (int u = 0; u < 3; ++u)
#pragma unroll
            for (int v = 0; v < 3; ++v) {
                int tp = u * 3 + v;
                int gy = py + u - 1, gx = px + v - 1;
                float p = ((unsigned)gy < HH && (unsigned)gx < WW) ? xc[gy * WW + gx] : 0.f;
                if (dbase + tp < KC) accA  = fmaf(p, wc[tp], accA);
                else                 accB2 = fmaf(p, wc[tp], accB2);
            }
    }
    float z = __fadd_rn(__fadd_rn(accA, accB2), bias[o]);
    out[idx] = (float)dec_np(z);
}

extern "C" void kernel_launch(void* const* d_in, const int* in_sizes, int n_in,
                              void* d_out, int out_size, void* d_ws, size_t ws_size,
                              hipStream_t stream) {
    const float* x  = (const float*)d_in[0];
    const float* Wt = (const float*)d_in[1];
    const float* bb = (const float*)d_in[2];
    float* out = (float*)d_out;

    const size_t WSPLIT   = (size_t)COUT * DD * 2;        // 147456 B each
    const size_t XP       = (size_t)NXP * 4;              // 27.56 MB padded
    const size_t XT       = (size_t)NX * 4;               // 25.69 MB HWC
    const size_t FIXED    = 2 * WSPLIT + XP + 4;
    const size_t FIXED_XT = 2 * WSPLIT + XP + XT + 4;

    if (ws_size >= FIXED + 65536) {
        int use_xt = (ws_size >= FIXED_XT + 65536) ? 1 : 0;
        unsigned short* Wph = (unsigned short*)d_ws;
        unsigned short* Wpl = Wph + COUT * DD;
        unsigned* xpad = (unsigned*)((char*)d_ws + 2 * WSPLIT);
        float*    xt   = (float*)((char*)d_ws + 2 * WSPLIT + XP);
        size_t tail = use_xt ? (2 * WSPLIT + XP + XT) : (2 * WSPLIT + XP);
        unsigned* wcount = (unsigned*)((char*)d_ws + tail);
        unsigned* wlist  = wcount + 1;
        size_t avail = (ws_size - tail - 4) / 4;
        unsigned wcap = (avail > 2000000u) ? 2000000u : (unsigned)avail;

        prep_all<<<dim3(NXP / 4 / 256), dim3(256), 0, stream>>>(
            x, Wt, xpad, Wph, Wpl, wcount, xt, use_xt);
        conv_mfma<<<dim3(1568), dim3(256), 0, stream>>>(xpad, Wph, Wpl, bb, out,
                                                        wcount, wlist, wcap);
        exact_fix_wave<<<dim3(4096), dim3(64), 0, stream>>>(
            x, Wt, bb, out, wcount, wlist, wcap, xt, use_xt);
    } else {
        np_emul_conv<<<(TOTAL + 255) / 256, 256, 0, stream>>>(x, Wt, bb, out);
    }
}

// Round 14
// 169.136 us; speedup vs baseline: 3.3011x; 1.2640x over previous
//
#include <hip/hip_runtime.h>
#include <math.h>

// B=32, Cin=64, H=W=56, Cout=128, K=3 pad=1 -> D=576, out (32,128,56,56) fp32
#define B_    32
#define CIN   64
#define HH    56
#define WW    56
#define COUT  128
#define DD    576
#define KC    384            // OpenBLAS kc split (verified R9)
#define LPX   (HH*WW)        // 3136 = 49*64
#define TOTAL (B_*COUT*LPX)
#define NX    (B_*CIN*LPX)   // 6422528
#define PW    58             // padded plane width/height
#define PPL   (PW*PW)        // 3364 words per padded channel plane
#define NXP   (B_*CIN*PPL)   // 6889472 words
#define MARGIN 4e-4f         // worst-case split-bf16 + reorder bound (validated R15-18)

typedef __attribute__((ext_vector_type(8)))  short  short8;
typedef __attribute__((ext_vector_type(16))) float  float16v;

__device__ __forceinline__ unsigned short bf16_rne(float f) {
    unsigned u = __float_as_uint(f);
    unsigned r = u + 0x7FFFu + ((u >> 16) & 1u);
    return (unsigned short)(r >> 16);
}
__device__ __forceinline__ float bf16_to_f(unsigned short h) {
    return __uint_as_float(((unsigned)h) << 16);
}

// ---- bit-exact numpy FLOAT_sin (npyv FMA path) — verified R9 ----
__device__ __forceinline__ float np_sinf(float x) {
#pragma clang fp contract(off)
    const float rint_cvt = 0x1.8p+23f;
    float q = __fmul_rn(x, 0x1.45f306p-1f);
    q = __fadd_rn(q, rint_cvt);
    q = __fsub_rn(q, rint_cvt);
    float r = fmaf(q, -0x1.921fb0p+0f, x);
    r = fmaf(q, -0x1.5110b4p-22f, r);
    r = fmaf(q, -0x1.846988p-48f, r);
    float r2 = __fmul_rn(r, r);
    float s = fmaf(0x1.7d3bbcp-19f, r2, -0x1.a06bbap-13f);
    s = fmaf(s, r2, 0x1.11119ap-7f);
    s = fmaf(s, r2, -0x1.555556p-3f);
    s = __fmul_rn(s, r2);
    s = fmaf(s, r, r);
    float c = fmaf(0x1.98e616p-16f, r2, -0x1.6c06dcp-10f);
    c = fmaf(c, r2, 0x1.55553cp-5f);
    c = fmaf(c, r2, -0.5f);
    c = fmaf(c, r2, 1.0f);
    int iq = (int)q;
    float res = (iq & 1) ? c : s;
    unsigned sgn = ((unsigned)(iq & 2)) << 30;
    return __uint_as_float(__float_as_uint(res) ^ sgn);
}
__device__ __forceinline__ int dec_np(float z) {
    float s = np_sinf(z);
    return (__fmul_rn(s, s) > 0.5f) ? 1 : 0;
}

// ---- merged prep (x4 vectorized, verified R9/R12): W -> fragment-major bf16
// hi/lo pack, x -> padded 58x58 planes of (hi | lo<<16) u32 words ----
// (x_t dropped: R13 showed it's worth <=3us; saves ~50MB of prep traffic.)
__global__ __launch_bounds__(256)
void prep_all(const float* __restrict__ x, const float* __restrict__ W,
              unsigned* __restrict__ xpad,
              unsigned short* __restrict__ Wph, unsigned short* __restrict__ Wpl) {
    int i4 = (blockIdx.x * 256 + threadIdx.x) * 4;
    if (i4 < COUT * DD) {               // COUT*DD % 4 == 0
#pragma unroll
        for (int e = 0; e < 4; ++e) {
            int i = i4 + e;
            int o = i / DD, k = i - o * DD;
            float w = W[i];
            unsigned short h = bf16_rne(w);
            unsigned short l = bf16_rne(w - bf16_to_f(h));
            int k18 = k >> 5, kr = k & 31;
            int s = (kr >> 4) & 1, half = (kr >> 3) & 1, j = kr & 7;
            int lane = half * 32 + (o & 31);
            int ot = o >> 5;
            unsigned dst = ((((unsigned)(k18 * 4 + ot)) * 2 + s) * 64 + lane) * 8 + j;
            Wph[dst] = h;
            Wpl[dst] = l;
        }
    }
    if (i4 < NXP) {                      // NXP % 4 == 0
        unsigned vv[4];
#pragma unroll
        for (int e = 0; e < 4; ++e) {
            int i = i4 + e;
            int bc = i / PPL;
            int r  = i - bc * PPL;
            int yy = r / PW;
            int xx = r - yy * PW;
            unsigned v = 0u;
            if (yy >= 1 && yy <= HH && xx >= 1 && xx <= WW) {
                float f = x[(size_t)bc * LPX + (yy - 1) * WW + (xx - 1)];
                unsigned short h = bf16_rne(f);
                unsigned short l = bf16_rne(f - bf16_to_f(h));
                v = (unsigned)h | ((unsigned)l << 16);
            }
            vv[e] = v;
        }
        *(uint4*)(xpad + i4) = *(uint4*)vv;
    }
}

// ---- MFMA conv with BLOCK-LOCAL fixup phase (R14). Main loop = EXACT R5/R12
// kernel (best measured ~100us, VGPR 60+32 AGPR, no spill). Epilogue records
// margin hits (avg ~4.2/block) into an LDS list (u16 local id, capacity 8192
// = bulletproof); after one barrier, the block runs the VERIFIED wave-coop
// fixup on its own list (4 waves x 1 elem/chunk; gather lane=channel; lane 0
// runs the bit-exact kc=384 chain + np_sinf). Deletes the 3rd kernel launch
// (R12/R13 ledger: its existence costs ~58us regardless of grid/layout).
// LDS: conv 16KB overlaid with sx/sw 18.4KB, + llist 16KB = ~35KB -> still
// 4 blocks/CU. NOT R11's failure: no call in the hot epilogue, fixup is a
// separate phase after acc is dead.
#define FRAG(t, s, hf, ln)  (((t) * 1024) + ((s) * 512) + ((hf) * 256) + ((ln) * 8))
#define SMEM_FIX  18432                  // sx[4][576] + sw[4][576] floats
#define SMEM_LIST 16384                  // ushort llist[8192]
__global__ __launch_bounds__(256, 4)
void conv_mfma(const unsigned* __restrict__ xpad,
               const unsigned short* __restrict__ Wph,
               const unsigned short* __restrict__ Wpl,
               const float* __restrict__ bias,
               float* __restrict__ out,
               const float* __restrict__ x,
               const float* __restrict__ Wt) {
    __shared__ __align__(16) char smem[SMEM_FIX + SMEM_LIST + 16];
    unsigned short* sP    = (unsigned short*)smem;        // conv: [hi|lo][2][2048]
    float*          sxB   = (float*)smem;                 // fixup overlay
    float*          swB   = sxB + 4 * DD;
    unsigned short* llist = (unsigned short*)(smem + SMEM_FIX);
    unsigned*       lcnt  = (unsigned*)(smem + SMEM_FIX + SMEM_LIST);

    const int tid = threadIdx.x;
    if (tid == 0) *lcnt = 0;             // published by first loop barrier
    // XCD-chunked bijective swizzle (1568 = 8*196): per-XCD contiguous chunk
    // = exactly 4 batches of xpad (~3.4MB -> fits 4MB L2).
    const int bid = (blockIdx.x & 7) * 196 + (blockIdx.x >> 3);
    const int pt0 = bid * 64;            // 64-px tile, never crosses a batch

    const int plane = tid & 15;
    const int pair  = tid >> 4;
    const int s_st  = pair >> 3;
    const int h_st  = (pair >> 2) & 1;
    const int j2_st = pair & 3;

    // per-r pixel bases into padded x (b folded in; LPX%64==0 so b-uniform)
    unsigned pbase[4];
#pragma unroll
    for (int r = 0; r < 4; ++r) {
        int gp = pt0 + plane + r * 16;
        int br = gp / LPX;
        int pr = gp - br * LPX;
        int ypx = pr / WW;
        int xpx = pr - ypx * WW;
        pbase[r] = (unsigned)(br * (CIN * PPL) + ypx * PW + xpx);
    }

    const int w    = tid >> 6;           // o-tile (0..3)
    const int lane = tid & 63;
    const int lm   = lane & 31;
    const int half = lane >> 5;
    const uint4* wAh = (const uint4*)Wph + w * 128 + lane;
    const uint4* wAl = (const uint4*)Wpl + w * 128 + lane;

    float16v acc[2];
#pragma unroll
    for (int n = 0; n < 2; ++n)
#pragma unroll
        for (int i = 0; i < 16; ++i) acc[n][i] = 0.f;

    unsigned pg[4][2], pgn[4][2];
    uint4 Ah[2], Al[2], Ahn[2], Aln[2];

#define LOADP(K0, DST)                                                         \
    {                                                                          \
        int d0 = (K0) + pair * 2;                                              \
        int c0 = d0 / 9, t0 = d0 - c0 * 9;                                     \
        int u0 = t0 / 3, v0 = t0 - u0 * 3;                                     \
        int t1 = t0 + 1, c1 = c0;                                              \
        if (t1 == 9) { t1 = 0; c1 = c0 + 1; }                                  \
        int u1 = t1 / 3, v1 = t1 - u1 * 3;                                     \
        unsigned off0 = (unsigned)(c0 * PPL + u0 * PW + v0);                   \
        unsigned off1 = (unsigned)(c1 * PPL + u1 * PW + v1);                   \
        _Pragma("unroll")                                                      \
        for (int r = 0; r < 4; ++r) {                                          \
            DST[r][0] = xpad[pbase[r] + off0];                                 \
            DST[r][1] = xpad[pbase[r] + off1];                                 \
        }                                                                      \
    }

#define LOADA(IT, DH, DL)                                                      \
    _Pragma("unroll")                                                          \
    for (int s = 0; s < 2; ++s) {                                              \
        DH[s] = wAh[(IT) * 512 + s * 64];                                      \
        DL[s] = wAl[(IT) * 512 + s * 64];                                      \
    }

    LOADP(0, pg)
    LOADA(0, Ah, Al)

#pragma unroll
    for (int it = 0; it < 18; ++it) {
        unsigned short* bPh = sP + (it & 1) * 2048;
        unsigned short* bPl = sP + 4096 + (it & 1) * 2048;

        // publish step it's patches (prefetched regs -> LDS)
#pragma unroll
        for (int r = 0; r < 4; ++r) {
            unsigned g0 = pg[r][0], g1 = pg[r][1];
            unsigned hw = (g0 & 0xFFFFu) | (g1 << 16);
            unsigned lw = (g0 >> 16) | (g1 & 0xFFFF0000u);
            int pm = plane + (r & 1) * 16;
            int word = (r >> 1) * 512 + s_st * 256 + h_st * 128 + pm * 4 + j2_st;
            ((unsigned*)bPh)[word] = hw;
            ((unsigned*)bPl)[word] = lw;
        }

        // issue next step's A + P loads; they land under the MFMA phase
        if (it < 17) {
            LOADA(it + 1, Ahn, Aln)
            LOADP((it + 1) * 32, pgn)
        }

        // drain own ds ops, rendezvous; prefetch loads stay in flight
        asm volatile("s_waitcnt lgkmcnt(0)" ::: "memory");
        __builtin_amdgcn_s_barrier();
        asm volatile("" ::: "memory");

#pragma unroll
        for (int n = 0; n < 2; ++n) {
            short8 Bh0 = *(const short8*)(bPh + FRAG(n, 0, half, lm));
            short8 Bl0 = *(const short8*)(bPl + FRAG(n, 0, half, lm));
            short8 Bh1 = *(const short8*)(bPh + FRAG(n, 1, half, lm));
            short8 Bl1 = *(const short8*)(bPl + FRAG(n, 1, half, lm));
            acc[n] = __builtin_amdgcn_mfma_f32_32x32x16_bf16(
                *(const short8*)&Ah[0], Bh0, acc[n], 0, 0, 0);
            acc[n] = __builtin_amdgcn_mfma_f32_32x32x16_bf16(
                *(const short8*)&Ah[0], Bl0, acc[n], 0, 0, 0);
            acc[n] = __builtin_amdgcn_mfma_f32_32x32x16_bf16(
                *(const short8*)&Al[0], Bh0, acc[n], 0, 0, 0);
            acc[n] = __builtin_amdgcn_mfma_f32_32x32x16_bf16(
                *(const short8*)&Ah[1], Bh1, acc[n], 0, 0, 0);
            acc[n] = __builtin_amdgcn_mfma_f32_32x32x16_bf16(
                *(const short8*)&Ah[1], Bl1, acc[n], 0, 0, 0);
            acc[n] = __builtin_amdgcn_mfma_f32_32x32x16_bf16(
                *(const short8*)&Al[1], Bh1, acc[n], 0, 0, 0);
        }

        if (it < 17) {
#pragma unroll
            for (int r = 0; r < 4; ++r) {
                pg[r][0] = pgn[r][0];
                pg[r][1] = pgn[r][1];
            }
#pragma unroll
            for (int s = 0; s < 2; ++s) {
                Ah[s] = Ahn[s];
                Al[s] = Aln[s];
            }
        }
    }
#undef LOADP
#undef LOADA

    // epilogue: provisional STE bit; record margin hits to block-local list
#pragma unroll
    for (int n = 0; n < 2; ++n) {
        const int gp0 = pt0 + n * 32;
        const int bpos = gp0 / LPX;
        const int pxb = gp0 - bpos * LPX + lm;
        const size_t outb = (size_t)bpos * COUT * LPX;
#pragma unroll
        for (int reg = 0; reg < 16; ++reg) {
            int o = w * 32 + 4 * half + (reg & 3) + 8 * (reg >> 2);
            float z = acc[n][reg] + bias[o];
            float q = rintf(__fmul_rn(z, 0.63661975f));
            float rr = fmaf(q, -1.5707964f, z);
            float d = fabsf(fabsf(rr) - 0.78539816f);
            size_t oidx = outb + (size_t)o * LPX + pxb;
            out[oidx] = (float)(((int)q) & 1);
            if (d < MARGIN) {
                unsigned p = atomicAdd(lcnt, 1u);
                llist[p] = (unsigned short)(tid * 32 + n * 16 + reg);
            }
        }
    }

    // ---- block-local wave-cooperative fixup phase (verified arithmetic) ----
    __syncthreads();                     // all hits recorded; sP dead
    const unsigned cnt = *lcnt;          // block-uniform
    const int wv = w;                    // wave id 0..3
    for (unsigned base = 0; base < cnt; base += 4) {
        __syncthreads();                 // sx/sw free (prev chunk consumed)
        unsigned ei = base + wv;
        int b_e = 0, o_e = 0, py_e = 0, px_e = 0;
        size_t idx_e = 0;
        if (ei < cnt) {
            unsigned e = llist[ei];
            int tid_e = e >> 5;
            int n_e   = (e >> 4) & 1;
            int reg_e = e & 15;
            o_e = ((tid_e >> 6) << 5) + 4 * ((tid_e & 63) >> 5)
                  + (reg_e & 3) + 8 * (reg_e >> 2);
            int gp = pt0 + n_e * 32 + (tid_e & 31);
            b_e = gp / LPX;
            int pix = gp - b_e * LPX;
            py_e = pix / WW;
            px_e = pix - py_e * WW;
            idx_e = (size_t)b_e * COUT * LPX + (size_t)o_e * LPX + pix;
            // gather: lane = channel c (byte-identical sx/sw to exact_fix_wave)
            const float* xc = x  + ((size_t)(b_e * CIN + lane)) * LPX;
            const float* wc = Wt + (size_t)o_e * DD + lane * 9;
#pragma unroll
            for (int u = 0; u < 3; ++u)
#pragma unroll
                for (int v = 0; v < 3; ++v) {
                    int tp = u * 3 + v;
                    int gy = py_e + u - 1, gx = px_e + v - 1;
                    float p = ((unsigned)gy < HH && (unsigned)gx < WW)
                                  ? xc[gy * WW + gx] : 0.f;
                    sxB[wv * DD + lane * 9 + tp] = p;
                    swB[wv * DD + lane * 9 + tp] = wc[tp];
                }
        }
        __syncthreads();
        if (ei < cnt && lane == 0) {
            const float* px_ = sxB + wv * DD;
            const float* pw_ = swB + wv * DD;
            float accA = 0.f, accB2 = 0.f;
            for (int d = 0; d < KC; ++d)        accA  = fmaf(px_[d], pw_[d], accA);
            for (int d = KC; d < DD; ++d)       accB2 = fmaf(px_[d], pw_[d], accB2);
            float zG = __fadd_rn(accA, accB2);
            float z  = __fadd_rn(zG, bias[o_e]);
            out[idx_e] = (float)dec_np(z);
        }
    }
}

// ---- fallback (verified R9 path) ----
__global__ __launch_bounds__(256)
void np_emul_conv(const float* __restrict__ x,
                  const float* __restrict__ Wt,
                  const float* __restrict__ bias,
                  float* __restrict__ out) {
#pragma clang fp contract(off)
    int idx = blockIdx.x * 256 + threadIdx.x;
    if (idx >= TOTAL) return;
    int px = idx % WW;
    int t  = idx / WW;
    int py = t % HH;  t /= HH;
    int o  = t % COUT;
    int b  = t / COUT;
    const float* wrow = Wt + (size_t)o * DD;
    const float* xb   = x + (size_t)b * CIN * LPX;
    float accA = 0.f, accB2 = 0.f;
    for (int c = 0; c < CIN; ++c) {
        const float* xc = xb + c * LPX;
        const float* wc = wrow + c * 9;
        int dbase = c * 9;
#pragma unroll
        for (int u = 0; u < 3; ++u)
#pragma unroll
            for (int v = 0; v < 3; ++v) {
                int tp = u * 3 + v;
                int gy = py + u - 1, gx = px + v - 1;
                float p = ((unsigned)gy < HH && (unsigned)gx < WW) ? xc[gy * WW + gx] : 0.f;
                if (dbase + tp < KC) accA  = fmaf(p, wc[tp], accA);
                else                 accB2 = fmaf(p, wc[tp], accB2);
            }
    }
    float z = __fadd_rn(__fadd_rn(accA, accB2), bias[o]);
    out[idx] = (float)dec_np(z);
}

extern "C" void kernel_launch(void* const* d_in, const int* in_sizes, int n_in,
                              void* d_out, int out_size, void* d_ws, size_t ws_size,
                              hipStream_t stream) {
    const float* x  = (const float*)d_in[0];
    const float* Wt = (const float*)d_in[1];
    const float* bb = (const float*)d_in[2];
    float* out = (float*)d_out;

    const size_t WSPLIT = (size_t)COUT * DD * 2;          // 147456 B each
    const size_t XP     = (size_t)NXP * 4;                // 27.56 MB padded
    const size_t FIXED  = 2 * WSPLIT + XP;

    if (ws_size >= FIXED + 4096) {
        unsigned short* Wph = (unsigned short*)d_ws;
        unsigned short* Wpl = Wph + COUT * DD;
        unsigned* xpad = (unsigned*)((char*)d_ws + 2 * WSPLIT);

        prep_all<<<dim3(NXP / 4 / 256), dim3(256), 0, stream>>>(x, Wt, xpad, Wph, Wpl);
        conv_mfma<<<dim3(1568), dim3(256), 0, stream>>>(xpad, Wph, Wpl, bb, out, x, Wt);
    } else {
        np_emul_conv<<<(TOTAL + 255) / 256, 256, 0, stream>>>(x, Wt, bb, out);
    }
}